// Round 1
// baseline (350.316 us; speedup 1.0000x reference)
//
#include <hip/hip_runtime.h>
#include <stdint.h>

// ---------- helpers ----------
typedef __attribute__((ext_vector_type(8))) short bf16x8;   // 8 bf16 in 4 VGPRs (guide-verified operand type)
typedef __attribute__((ext_vector_type(4))) float f32x4;

__device__ __forceinline__ unsigned short f2bf(float f) {
  union { float f; unsigned u; } v; v.f = f;
  unsigned r = v.u + 0x7fffu + ((v.u >> 16) & 1u);   // RNE
  return (unsigned short)(r >> 16);
}
__device__ __forceinline__ float bf2f(unsigned short u) {
  union { unsigned u; float f; } v; v.u = ((unsigned)u) << 16; return v.f;
}

// async global->LDS, 16B per lane, dest = wave-uniform base + lane*16 (CK-style casts)
__device__ __forceinline__ void gload16(const void* g, void* l) {
  __builtin_amdgcn_global_load_lds(
      (const __attribute__((address_space(1))) unsigned int*)(uintptr_t)g,
      (__attribute__((address_space(3))) unsigned int*)(uintptr_t)l,
      16, 0, 0);
}

// ---------- kernel 1: fused gate network + LayerNorm + bf16 z-stack ----------
// one block (256 thr) per row; each thread owns 4 consecutive f32 of the row.
__global__ __launch_bounds__(256)
void k_gate_ln(const float* __restrict__ x, const int* __restrict__ dmask,
               const float* __restrict__ gw1, const float* __restrict__ gb1,
               const float* __restrict__ gw2, const float* __restrict__ gb2,
               const float* __restrict__ sb, const float* __restrict__ bb,
               const float* __restrict__ si, const float* __restrict__ bi,
               float* __restrict__ wout,          // [rows][4] f32: w0,w1,w2,0
               unsigned short* __restrict__ z)    // [2*rows][1024] bf16
{
  const int row = blockIdx.x;
  const int t = threadIdx.x;
  const float4 xv = *(const float4*)(x + (size_t)row * 1024 + t * 4);
  const float xs[4] = {xv.x, xv.y, xv.z, xv.w};

  float p0 = 0.f, p1 = 0.f, p2 = 0.f, p3 = 0.f;
#pragma unroll
  for (int j = 0; j < 4; ++j) {
    const float4 w = *(const float4*)(gw1 + (size_t)(t * 4 + j) * 4);
    p0 += xs[j] * w.x; p1 += xs[j] * w.y; p2 += xs[j] * w.z; p3 += xs[j] * w.w;
  }
  float s  = xs[0] + xs[1] + xs[2] + xs[3];
  float ss = xs[0]*xs[0] + xs[1]*xs[1] + xs[2]*xs[2] + xs[3]*xs[3];

  __shared__ float red[6 * 256];
  __shared__ float bc[2];
  red[0*256 + t] = p0; red[1*256 + t] = p1; red[2*256 + t] = p2;
  red[3*256 + t] = p3; red[4*256 + t] = s;  red[5*256 + t] = ss;
  __syncthreads();
  for (int st = 128; st > 0; st >>= 1) {
    if (t < st) {
#pragma unroll
      for (int c = 0; c < 6; ++c) red[c*256 + t] += red[c*256 + t + st];
    }
    __syncthreads();
  }
  if (t == 0) {
    float h0 = fmaxf(red[0*256] + gb1[0], 0.f);
    float h1 = fmaxf(red[1*256] + gb1[1], 0.f);
    float h2 = fmaxf(red[2*256] + gb1[2], 0.f);
    float h3 = fmaxf(red[3*256] + gb1[3], 0.f);
    float lg[4];
#pragma unroll
    for (int e = 0; e < 4; ++e) {
      float v = h0*gw2[0*4+e] + h1*gw2[1*4+e] + h2*gw2[2*4+e] + h3*gw2[3*4+e] + gb2[e];
      lg[e] = (dmask[e] == 0) ? -1.0e9f : v;
    }
    float m = fmaxf(fmaxf(lg[0], lg[1]), fmaxf(lg[2], lg[3]));
    float e0 = expf(lg[0]-m), e1 = expf(lg[1]-m), e2 = expf(lg[2]-m), e3 = expf(lg[3]-m);
    float inv = 1.f / (e0 + e1 + e2 + e3);
    float4 wv; wv.x = e0*inv; wv.y = e1*inv; wv.z = e2*inv; wv.w = 0.f;
    *(float4*)(wout + (size_t)row * 4) = wv;
    float mean = red[4*256] * (1.f/1024.f);
    float var  = red[5*256] * (1.f/1024.f) - mean * mean;
    bc[0] = mean; bc[1] = rsqrtf(var + 1e-6f);
  }
  __syncthreads();
  const float mean = bc[0], rstd = bc[1];

  const float4 sbv = *(const float4*)(sb + t*4);
  const float4 bbv = *(const float4*)(bb + t*4);
  const float4 siv = *(const float4*)(si + t*4);
  const float4 biv = *(const float4*)(bi + t*4);
  const float sbs[4] = {sbv.x, sbv.y, sbv.z, sbv.w};
  const float bbs[4] = {bbv.x, bbv.y, bbv.z, bbv.w};
  const float sis[4] = {siv.x, siv.y, siv.z, siv.w};
  const float bis[4] = {biv.x, biv.y, biv.z, biv.w};
  ushort4 zb, zi;
  unsigned short zbv[4], ziv[4];
#pragma unroll
  for (int j = 0; j < 4; ++j) {
    float xn = (xs[j] - mean) * rstd;
    zbv[j] = f2bf(xn * sbs[j] + bbs[j]);
    ziv[j] = f2bf(xn * sis[j] + bis[j]);
  }
  zb.x = zbv[0]; zb.y = zbv[1]; zb.z = zbv[2]; zb.w = zbv[3];
  zi.x = ziv[0]; zi.y = ziv[1]; zi.z = ziv[2]; zi.w = ziv[3];
  *(ushort4*)(z + (size_t)row * 1024 + t * 4) = zb;
  *(ushort4*)(z + (size_t)(8192 + row) * 1024 + t * 4) = zi;
}

// ---------- kernel 2: f32 (R,C) -> bf16 transposed (C,R) ----------
__global__ __launch_bounds__(256)
void k_transpose_bf16(const float* __restrict__ src, unsigned short* __restrict__ dst,
                      int R, int C)
{
  __shared__ float tile[32][33];
  const int tx = threadIdx.x & 31, ty = threadIdx.x >> 5;  // 32 x 8
  const int c0 = blockIdx.x * 32, r0 = blockIdx.y * 32;
#pragma unroll
  for (int j = 0; j < 32; j += 8)
    tile[ty + j][tx] = src[(size_t)(r0 + ty + j) * C + c0 + tx];
  __syncthreads();
#pragma unroll
  for (int j = 0; j < 32; j += 8)
    dst[(size_t)(c0 + ty + j) * R + r0 + tx] = f2bf(tile[tx][ty + j]);
}

// ---------- kernel 3: bf16 GEMM, C = act(A @ Bt^T + bias), m97 structure ----------
// A: M x K bf16 row-major; Bt: N x K bf16 row-major; C: M x N bf16.
// 128x128 tile, BK=32, 4 waves (2x2 of 64x64), global_load_lds(16B), linear LDS.
template <int RELU>
__global__ __launch_bounds__(256)
void gemm_bt_128(const unsigned short* __restrict__ A,
                 const unsigned short* __restrict__ Bt,
                 const float* __restrict__ bias,
                 unsigned short* __restrict__ C,
                 int M, int N, int K)
{
  __shared__ __align__(16) unsigned short lds_a[128 * 32];
  __shared__ __align__(16) unsigned short lds_b[128 * 32];
  const int tid = threadIdx.x;
  const int wave = tid >> 6;
  const int lane = tid & 63;
  const int bm0 = blockIdx.y * 128;
  const int bn0 = blockIdx.x * 128;
  const int wr = wave >> 1, wc = wave & 1;

  f32x4 acc[4][4] = {};

  // staging: tile = 128 rows x 32 k of bf16 (8KB) = 512 chunks of 16B; 256 thr -> 2 rounds
  const int c0i = tid, c1i = tid + 256;
  const int rA0 = c0i >> 2, kk0 = (c0i & 3) * 8;
  const int rA1 = c1i >> 2, kk1 = (c1i & 3) * 8;
  char* la0 = (char*)lds_a + wave * 1024;
  char* la1 = (char*)lds_a + 4096 + wave * 1024;
  char* lb0 = (char*)lds_b + wave * 1024;
  char* lb1 = (char*)lds_b + 4096 + wave * 1024;
  const unsigned short* Abase = A + (size_t)bm0 * K;
  const unsigned short* Bbase = Bt + (size_t)bn0 * K;

  const int lr = lane & 15;
  const int lkb = (lane >> 4) * 16;   // byte offset inside 64B LDS row

  for (int k0 = 0; k0 < K; k0 += 32) {
    __syncthreads();   // previous compute done before overwrite
    gload16(Abase + (size_t)rA0 * K + k0 + kk0, la0);
    gload16(Abase + (size_t)rA1 * K + k0 + kk1, la1);
    gload16(Bbase + (size_t)rA0 * K + k0 + kk0, lb0);
    gload16(Bbase + (size_t)rA1 * K + k0 + kk1, lb1);
    __syncthreads();   // compiler drains vmcnt before barrier -> LDS ready

    bf16x8 af[4], bfr[4];
#pragma unroll
    for (int mi = 0; mi < 4; ++mi)
      af[mi] = *(const bf16x8*)((const char*)lds_a + (wr*64 + mi*16 + lr) * 64 + lkb);
#pragma unroll
    for (int ni = 0; ni < 4; ++ni)
      bfr[ni] = *(const bf16x8*)((const char*)lds_b + (wc*64 + ni*16 + lr) * 64 + lkb);
#pragma unroll
    for (int mi = 0; mi < 4; ++mi)
#pragma unroll
      for (int ni = 0; ni < 4; ++ni)
        acc[mi][ni] = __builtin_amdgcn_mfma_f32_16x16x32_bf16(af[mi], bfr[ni], acc[mi][ni], 0, 0, 0);
  }

  // epilogue: C/D layout (verified): col = lane&15, row = (lane>>4)*4 + j
#pragma unroll
  for (int ni = 0; ni < 4; ++ni) {
    const int col = bn0 + wc*64 + ni*16 + lr;
    const float bv = bias[col];
#pragma unroll
    for (int mi = 0; mi < 4; ++mi) {
      const int r0 = bm0 + wr*64 + mi*16 + (lane >> 4) * 4;
#pragma unroll
      for (int j = 0; j < 4; ++j) {
        float v = acc[mi][ni][j] + bv;
        if (RELU) v = fmaxf(v, 0.f);
        C[(size_t)(r0 + j) * N + col] = f2bf(v);
      }
    }
  }
}

// ---------- kernel 4: final mix ----------
// out = x*(1+w0) + w1*a_book + w2*a_iwslt
__global__ __launch_bounds__(256)
void k_mix(const float* __restrict__ x, const float* __restrict__ w,
           const unsigned short* __restrict__ a, float* __restrict__ out)
{
  const int row = blockIdx.x;
  const int t = threadIdx.x;
  const float4 wv = *(const float4*)(w + (size_t)row * 4);
  const float4 xv = *(const float4*)(x + (size_t)row * 1024 + t * 4);
  const ushort4 ab = *(const ushort4*)(a + (size_t)row * 1024 + t * 4);
  const ushort4 ai = *(const ushort4*)(a + (size_t)(8192 + row) * 1024 + t * 4);
  float4 o;
  o.x = xv.x * (1.f + wv.x) + wv.y * bf2f(ab.x) + wv.z * bf2f(ai.x);
  o.y = xv.y * (1.f + wv.x) + wv.y * bf2f(ab.y) + wv.z * bf2f(ai.y);
  o.z = xv.z * (1.f + wv.x) + wv.y * bf2f(ab.z) + wv.z * bf2f(ai.z);
  o.w = xv.w * (1.f + wv.x) + wv.y * bf2f(ab.w) + wv.z * bf2f(ai.w);
  *(float4*)(out + (size_t)row * 1024 + t * 4) = o;
}

// ---------- launch ----------
extern "C" void kernel_launch(void* const* d_in, const int* in_sizes, int n_in,
                              void* d_out, int out_size, void* d_ws, size_t ws_size,
                              hipStream_t stream) {
  const float* x    = (const float*)d_in[0];
  const int*   dm   = (const int*)  d_in[1];
  const float* gw1  = (const float*)d_in[2];
  const float* gb1  = (const float*)d_in[3];
  const float* gw2  = (const float*)d_in[4];
  const float* gb2  = (const float*)d_in[5];
  const float* lsb  = (const float*)d_in[6];
  const float* lbb  = (const float*)d_in[7];
  const float* lsi  = (const float*)d_in[8];
  const float* lbi  = (const float*)d_in[9];
  const float* aw1  = (const float*)d_in[10];
  const float* ab1  = (const float*)d_in[11];
  const float* aw2  = (const float*)d_in[12];
  const float* ab2  = (const float*)d_in[13];
  float* out = (float*)d_out;

  // workspace layout (bytes). abuf aliases z (z fully consumed by GEMM1 before GEMM2 writes).
  char* ws = (char*)d_ws;
  float*          wgt  = (float*)(ws + 0);                         // 8192*4*4   = 131072
  unsigned short* z    = (unsigned short*)(ws + 131072);           // 16384*1024*2 = 33554432
  unsigned short* abuf = z;                                        // alias (same shape)
  unsigned short* w1t  = (unsigned short*)(ws + 131072 + 33554432);            // 2048*1024*2
  unsigned short* w2t  = (unsigned short*)(ws + 131072 + 33554432 + 4194304);  // 1024*2048*2
  unsigned short* hbuf = (unsigned short*)(ws + 131072 + 33554432 + 8388608);  // 16384*2048*2

  k_gate_ln<<<8192, 256, 0, stream>>>(x, dm, gw1, gb1, gw2, gb2,
                                      lsb, lbb, lsi, lbi, wgt, z);
  k_transpose_bf16<<<dim3(2048/32, 1024/32), 256, 0, stream>>>(aw1, w1t, 1024, 2048);
  k_transpose_bf16<<<dim3(1024/32, 2048/32), 256, 0, stream>>>(aw2, w2t, 2048, 1024);
  // GEMM1: h = relu(z @ w1 + b1)   [16384 x 2048]
  gemm_bt_128<1><<<dim3(2048/128, 16384/128), 256, 0, stream>>>(z, w1t, ab1, hbuf, 16384, 2048, 1024);
  // GEMM2: a = h @ w2 + b2         [16384 x 1024]
  gemm_bt_128<0><<<dim3(1024/128, 16384/128), 256, 0, stream>>>(hbuf, w2t, ab2, abuf, 16384, 1024, 2048);
  k_mix<<<8192, 256, 0, stream>>>(x, wgt, abuf, out);
}

// Round 2
// 293.494 us; speedup vs baseline: 1.1936x; 1.1936x over previous
//
#include <hip/hip_runtime.h>
#include <stdint.h>

// ---------- helpers ----------
typedef __attribute__((ext_vector_type(8))) short bf16x8;
typedef __attribute__((ext_vector_type(4))) float f32x4;

__device__ __forceinline__ unsigned short f2bf(float f) {
  union { float f; unsigned u; } v; v.f = f;
  unsigned r = v.u + 0x7fffu + ((v.u >> 16) & 1u);   // RNE
  return (unsigned short)(r >> 16);
}
__device__ __forceinline__ float bf2f(unsigned short u) {
  union { unsigned u; float f; } v; v.u = ((unsigned)u) << 16; return v.f;
}
__device__ __forceinline__ void gload16(const void* g, void* l) {
  __builtin_amdgcn_global_load_lds(
      (const __attribute__((address_space(1))) unsigned int*)(uintptr_t)g,
      (__attribute__((address_space(3))) unsigned int*)(uintptr_t)l,
      16, 0, 0);
}

// ---------- kernel 1: fused gate network + LayerNorm + bf16 z-stack ----------
__global__ __launch_bounds__(256)
void k_gate_ln(const float* __restrict__ x, const int* __restrict__ dmask,
               const float* __restrict__ gw1, const float* __restrict__ gb1,
               const float* __restrict__ gw2, const float* __restrict__ gb2,
               const float* __restrict__ sb, const float* __restrict__ bb,
               const float* __restrict__ si, const float* __restrict__ bi,
               float* __restrict__ wout,          // [rows][4] f32: w0,w1,w2,0
               unsigned short* __restrict__ z)    // [2*rows][1024] bf16
{
  const int row = blockIdx.x;
  const int t = threadIdx.x;
  const int wave = t >> 6, lane = t & 63;
  const float4 xv = *(const float4*)(x + (size_t)row * 1024 + t * 4);
  const float xs[4] = {xv.x, xv.y, xv.z, xv.w};

  float v[6];
  v[0] = v[1] = v[2] = v[3] = 0.f;
#pragma unroll
  for (int j = 0; j < 4; ++j) {
    const float4 w = *(const float4*)(gw1 + (size_t)(t * 4 + j) * 4);
    v[0] += xs[j] * w.x; v[1] += xs[j] * w.y; v[2] += xs[j] * w.z; v[3] += xs[j] * w.w;
  }
  v[4] = xs[0] + xs[1] + xs[2] + xs[3];
  v[5] = xs[0]*xs[0] + xs[1]*xs[1] + xs[2]*xs[2] + xs[3]*xs[3];

  // wave-level reduce (64 lanes), then cross-wave via LDS
#pragma unroll
  for (int off = 32; off > 0; off >>= 1)
#pragma unroll
    for (int c = 0; c < 6; ++c) v[c] += __shfl_down(v[c], off, 64);

  __shared__ float wsum[4][6];
  __shared__ float bc[2];
  if (lane == 0)
#pragma unroll
    for (int c = 0; c < 6; ++c) wsum[wave][c] = v[c];
  __syncthreads();
  if (t == 0) {
    float r[6];
#pragma unroll
    for (int c = 0; c < 6; ++c) r[c] = wsum[0][c] + wsum[1][c] + wsum[2][c] + wsum[3][c];
    float h0 = fmaxf(r[0] + gb1[0], 0.f);
    float h1 = fmaxf(r[1] + gb1[1], 0.f);
    float h2 = fmaxf(r[2] + gb1[2], 0.f);
    float h3 = fmaxf(r[3] + gb1[3], 0.f);
    float lg[4];
#pragma unroll
    for (int e = 0; e < 4; ++e) {
      float val = h0*gw2[0*4+e] + h1*gw2[1*4+e] + h2*gw2[2*4+e] + h3*gw2[3*4+e] + gb2[e];
      lg[e] = (dmask[e] == 0) ? -1.0e9f : val;
    }
    float m = fmaxf(fmaxf(lg[0], lg[1]), fmaxf(lg[2], lg[3]));
    float e0 = expf(lg[0]-m), e1 = expf(lg[1]-m), e2 = expf(lg[2]-m), e3 = expf(lg[3]-m);
    float inv = 1.f / (e0 + e1 + e2 + e3);
    float4 wv; wv.x = e0*inv; wv.y = e1*inv; wv.z = e2*inv; wv.w = 0.f;
    *(float4*)(wout + (size_t)row * 4) = wv;
    float mean = r[4] * (1.f/1024.f);
    float var  = r[5] * (1.f/1024.f) - mean * mean;
    bc[0] = mean; bc[1] = rsqrtf(var + 1e-6f);
  }
  __syncthreads();
  const float mean = bc[0], rstd = bc[1];

  const float4 sbv = *(const float4*)(sb + t*4);
  const float4 bbv = *(const float4*)(bb + t*4);
  const float4 siv = *(const float4*)(si + t*4);
  const float4 biv = *(const float4*)(bi + t*4);
  const float sbs[4] = {sbv.x, sbv.y, sbv.z, sbv.w};
  const float bbs[4] = {bbv.x, bbv.y, bbv.z, bbv.w};
  const float sis[4] = {siv.x, siv.y, siv.z, siv.w};
  const float bis[4] = {biv.x, biv.y, biv.z, biv.w};
  ushort4 zb, zi;
  unsigned short zbv[4], ziv[4];
#pragma unroll
  for (int j = 0; j < 4; ++j) {
    float xn = (xs[j] - mean) * rstd;
    zbv[j] = f2bf(xn * sbs[j] + bbs[j]);
    ziv[j] = f2bf(xn * sis[j] + bis[j]);
  }
  zb.x = zbv[0]; zb.y = zbv[1]; zb.z = zbv[2]; zb.w = zbv[3];
  zi.x = ziv[0]; zi.y = ziv[1]; zi.z = ziv[2]; zi.w = ziv[3];
  *(ushort4*)(z + (size_t)row * 1024 + t * 4) = zb;
  *(ushort4*)(z + (size_t)(8192 + row) * 1024 + t * 4) = zi;
}

// ---------- kernel 2: f32 (R,C) -> bf16 transposed (C,R) ----------
__global__ __launch_bounds__(256)
void k_transpose_bf16(const float* __restrict__ src, unsigned short* __restrict__ dst,
                      int R, int C)
{
  __shared__ float tile[32][33];
  const int tx = threadIdx.x & 31, ty = threadIdx.x >> 5;
  const int c0 = blockIdx.x * 32, r0 = blockIdx.y * 32;
#pragma unroll
  for (int j = 0; j < 32; j += 8)
    tile[ty + j][tx] = src[(size_t)(r0 + ty + j) * C + c0 + tx];
  __syncthreads();
#pragma unroll
  for (int j = 0; j < 32; j += 8)
    dst[(size_t)(c0 + ty + j) * R + r0 + tx] = f2bf(tile[tx][ty + j]);
}

// ---------- kernel 3: 256x256 8-phase bf16 GEMM (m201 structure) ----------
// A: M x K bf16 row-major; Bt: N x K bf16 row-major; C = act(A@Bt^T + bias) bf16 M x N.
// 512 thr = 8 waves (2M x 4N), BK=64, LDS 128KB double-buffer.
// LDS per buffer: A[256][64] @ +0 (32KB), B[256][64] @ +32768. buf b at b*65536.
// Swizzle: 16B-chunk index ^= (row&7), applied on global SOURCE (linear gload_lds dest)
// and on ds_read address (rule #21: both-sides-or-neither).
// Stage stream H[j]: tile j>>2, half j&3 in order {B-lo,B-hi,A-lo,A-hi}; prologue 6,
// phase (t,q) stages H[6+4t+q] -> every overwrite issues >=1 barrier after the
// region's last read (race-free by construction); counted vmcnt(4) once per K-tile.
template <int RELU, int K, int NBX>
__global__ __launch_bounds__(512, 2)
void gemm256(const unsigned short* __restrict__ A,
             const unsigned short* __restrict__ Bt,
             const float* __restrict__ bias,
             unsigned short* __restrict__ C)
{
  constexpr int NKT = K / 64;
  constexpr int N = NBX * 256;
  __shared__ __align__(16) char lds[131072];

  const int tid = threadIdx.x;
  const int wave = tid >> 6, lane = tid & 63;
  const int lr = lane & 15, lk = lane >> 4;
  const int wm = wave >> 2, wn = wave & 3;

  // XCD-aware bijective block swizzle (gridDim.x % 8 == 0 by construction)
  const int cpx = (int)gridDim.x >> 3;
  const int flat = (int)blockIdx.x;
  const int swz = (flat & 7) * cpx + (flat >> 3);
  const int bm0 = (swz / NBX) * 256;
  const int bn0 = (swz % NBX) * 256;

  // staging source (inverse-swizzled global address; LDS dest stays linear)
  const int srow = tid >> 3;
  const int schunk = ((tid & 7) ^ (srow & 7)) * 8;
  const unsigned short* aSrc = A + (size_t)(bm0 + srow) * K + schunk;
  const unsigned short* bSrc = Bt + (size_t)(bn0 + srow) * K + schunk;
  const int ldsWaveOff = wave * 1024;

  // read-side swizzled k-offsets
  const int xorv = (lr & 7) << 4;
  const int koff0 = (lk * 16) ^ xorv;
  const int koff1 = (64 + lk * 16) ^ xorv;
  const int arowB = wm * 128 + lr;
  const int browB = wn * 64 + lr;

  f32x4 acc[8][4] = {};

  auto stage = [&](int j) {
    if (j >= 4 * NKT) return;
    const int tile = j >> 2, h = j & 3;
    const unsigned short* s = (h < 2 ? bSrc : aSrc) + (size_t)((h & 1) * 128) * K + tile * 64;
    char* d = lds + ((tile & 1) << 16) + ((h < 2) ? 32768 : 0) + ((h & 1) << 14) + ldsWaveOff;
    gload16(s, d);
    gload16(s + (size_t)64 * K, d + 8192);
  };

  // prologue: tile0 complete + tile1 B halves
  stage(0); stage(1); stage(2); stage(3); stage(4); stage(5);
  asm volatile("s_waitcnt vmcnt(4)" ::: "memory");   // tile 0 landed (all 8 loads/wave... 4 outstanding = tile1 B)
  __builtin_amdgcn_s_barrier();

  for (int t = 0; t < NKT; ++t) {
    const char* curA = lds + ((t & 1) << 16);
    const char* curB = curA + 32768;
    const int jb = 6 + 4 * t;
    bf16x8 bf[4][2];
    bf16x8 af[2][2];

#pragma unroll
    for (int q = 0; q < 4; ++q) {
      if (q == 0) {
#pragma unroll
        for (int ni = 0; ni < 4; ++ni) {
          bf[ni][0] = *(const bf16x8*)(curB + (browB + ni * 16) * 128 + koff0);
          bf[ni][1] = *(const bf16x8*)(curB + (browB + ni * 16) * 128 + koff1);
        }
      }
#pragma unroll
      for (int i = 0; i < 2; ++i) {
        af[i][0] = *(const bf16x8*)(curA + (arowB + (2 * q + i) * 16) * 128 + koff0);
        af[i][1] = *(const bf16x8*)(curA + (arowB + (2 * q + i) * 16) * 128 + koff1);
      }
      stage(jb + q);
      if (q == 3) {
        if (t < NKT - 2)       asm volatile("s_waitcnt vmcnt(4)" ::: "memory");
        else if (t == NKT - 2) asm volatile("s_waitcnt vmcnt(0)" ::: "memory");
      }
      __builtin_amdgcn_s_barrier();
      asm volatile("s_waitcnt lgkmcnt(0)" ::: "memory");
      __builtin_amdgcn_s_setprio(1);
#pragma unroll
      for (int i = 0; i < 2; ++i)
#pragma unroll
        for (int ni = 0; ni < 4; ++ni) {
          acc[2 * q + i][ni] = __builtin_amdgcn_mfma_f32_16x16x32_bf16(af[i][0], bf[ni][0], acc[2 * q + i][ni], 0, 0, 0);
          acc[2 * q + i][ni] = __builtin_amdgcn_mfma_f32_16x16x32_bf16(af[i][1], bf[ni][1], acc[2 * q + i][ni], 0, 0, 0);
        }
      __builtin_amdgcn_s_setprio(0);
      __builtin_amdgcn_s_barrier();
    }
  }

  // epilogue: C/D layout col=lane&15, row=(lane>>4)*4+j
#pragma unroll
  for (int ni = 0; ni < 4; ++ni) {
    const int col = bn0 + wn * 64 + ni * 16 + lr;
    const float bv = bias[col];
#pragma unroll
    for (int mi = 0; mi < 8; ++mi) {
      const int r0 = bm0 + wm * 128 + mi * 16 + lk * 4;
#pragma unroll
      for (int j = 0; j < 4; ++j) {
        float v = acc[mi][ni][j] + bv;
        if (RELU) v = fmaxf(v, 0.f);
        C[(size_t)(r0 + j) * N + col] = f2bf(v);
      }
    }
  }
}

// ---------- kernel 4: final mix ----------
__global__ __launch_bounds__(256)
void k_mix(const float* __restrict__ x, const float* __restrict__ w,
           const unsigned short* __restrict__ a, float* __restrict__ out)
{
  const int row = blockIdx.x;
  const int t = threadIdx.x;
  const float4 wv = *(const float4*)(w + (size_t)row * 4);
  const float4 xv = *(const float4*)(x + (size_t)row * 1024 + t * 4);
  const ushort4 ab = *(const ushort4*)(a + (size_t)row * 1024 + t * 4);
  const ushort4 ai = *(const ushort4*)(a + (size_t)(8192 + row) * 1024 + t * 4);
  float4 o;
  o.x = xv.x * (1.f + wv.x) + wv.y * bf2f(ab.x) + wv.z * bf2f(ai.x);
  o.y = xv.y * (1.f + wv.x) + wv.y * bf2f(ab.y) + wv.z * bf2f(ai.y);
  o.z = xv.z * (1.f + wv.x) + wv.y * bf2f(ab.z) + wv.z * bf2f(ai.z);
  o.w = xv.w * (1.f + wv.x) + wv.y * bf2f(ab.w) + wv.z * bf2f(ai.w);
  *(float4*)(out + (size_t)row * 1024 + t * 4) = o;
}

// ---------- launch ----------
extern "C" void kernel_launch(void* const* d_in, const int* in_sizes, int n_in,
                              void* d_out, int out_size, void* d_ws, size_t ws_size,
                              hipStream_t stream) {
  const float* x    = (const float*)d_in[0];
  const int*   dm   = (const int*)  d_in[1];
  const float* gw1  = (const float*)d_in[2];
  const float* gb1  = (const float*)d_in[3];
  const float* gw2  = (const float*)d_in[4];
  const float* gb2  = (const float*)d_in[5];
  const float* lsb  = (const float*)d_in[6];
  const float* lbb  = (const float*)d_in[7];
  const float* lsi  = (const float*)d_in[8];
  const float* lbi  = (const float*)d_in[9];
  const float* aw1  = (const float*)d_in[10];
  const float* ab1  = (const float*)d_in[11];
  const float* aw2  = (const float*)d_in[12];
  const float* ab2  = (const float*)d_in[13];
  float* out = (float*)d_out;

  char* ws = (char*)d_ws;
  float*          wgt  = (float*)(ws + 0);                                     // 128KB
  unsigned short* z    = (unsigned short*)(ws + 131072);                       // 32MB
  unsigned short* abuf = z;                                                    // alias
  unsigned short* w1t  = (unsigned short*)(ws + 131072 + 33554432);            // 4MB
  unsigned short* w2t  = (unsigned short*)(ws + 131072 + 33554432 + 4194304);  // 4MB
  unsigned short* hbuf = (unsigned short*)(ws + 131072 + 33554432 + 8388608);  // 64MB

  k_gate_ln<<<8192, 256, 0, stream>>>(x, dm, gw1, gb1, gw2, gb2,
                                      lsb, lbb, lsi, lbi, wgt, z);
  k_transpose_bf16<<<dim3(2048/32, 1024/32), 256, 0, stream>>>(aw1, w1t, 1024, 2048);
  k_transpose_bf16<<<dim3(1024/32, 2048/32), 256, 0, stream>>>(aw2, w2t, 2048, 1024);
  // GEMM1: h = relu(z @ w1 + b1)   [16384 x 2048], K=1024
  gemm256<1, 1024, 8><<<512, 512, 0, stream>>>(z, w1t, ab1, hbuf);
  // GEMM2: a = h @ w2 + b2         [16384 x 1024], K=2048
  gemm256<0, 2048, 4><<<256, 512, 0, stream>>>(hbuf, w2t, ab2, abuf);
  k_mix<<<8192, 256, 0, stream>>>(x, wgt, abuf, out);
}

// Round 3
// 261.327 us; speedup vs baseline: 1.3405x; 1.1231x over previous
//
#include <hip/hip_runtime.h>
#include <stdint.h>

// ---------- helpers ----------
typedef __attribute__((ext_vector_type(8))) short bf16x8;
typedef __attribute__((ext_vector_type(4))) float f32x4;

__device__ __forceinline__ unsigned short f2bf(float f) {
  union { float f; unsigned u; } v; v.f = f;
  unsigned r = v.u + 0x7fffu + ((v.u >> 16) & 1u);   // RNE
  return (unsigned short)(r >> 16);
}
__device__ __forceinline__ float bf2f(unsigned short u) {
  union { unsigned u; float f; } v; v.u = ((unsigned)u) << 16; return v.f;
}
__device__ __forceinline__ void gload16(const void* g, void* l) {
  __builtin_amdgcn_global_load_lds(
      (const __attribute__((address_space(1))) unsigned int*)(uintptr_t)g,
      (__attribute__((address_space(3))) unsigned int*)(uintptr_t)l,
      16, 0, 0);
}

// ---------- kernel 1: fused gate network + LayerNorm + bf16 z-stack (interleaved) ----------
// z rows: 2*row = book, 2*row+1 = iwslt  (pairs same original row for GEMM2 mix fusion)
__global__ __launch_bounds__(256)
void k_gate_ln(const float* __restrict__ x, const int* __restrict__ dmask,
               const float* __restrict__ gw1, const float* __restrict__ gb1,
               const float* __restrict__ gw2, const float* __restrict__ gb2,
               const float* __restrict__ sb, const float* __restrict__ bb,
               const float* __restrict__ si, const float* __restrict__ bi,
               float* __restrict__ wout,          // [rows][4] f32: w0,w1,w2,0
               unsigned short* __restrict__ z)    // [2*rows][1024] bf16 interleaved
{
  const int row = blockIdx.x;
  const int t = threadIdx.x;
  const int wave = t >> 6, lane = t & 63;
  const float4 xv = *(const float4*)(x + (size_t)row * 1024 + t * 4);
  const float xs[4] = {xv.x, xv.y, xv.z, xv.w};

  float v[6];
  v[0] = v[1] = v[2] = v[3] = 0.f;
#pragma unroll
  for (int j = 0; j < 4; ++j) {
    const float4 w = *(const float4*)(gw1 + (size_t)(t * 4 + j) * 4);
    v[0] += xs[j] * w.x; v[1] += xs[j] * w.y; v[2] += xs[j] * w.z; v[3] += xs[j] * w.w;
  }
  v[4] = xs[0] + xs[1] + xs[2] + xs[3];
  v[5] = xs[0]*xs[0] + xs[1]*xs[1] + xs[2]*xs[2] + xs[3]*xs[3];

#pragma unroll
  for (int off = 32; off > 0; off >>= 1)
#pragma unroll
    for (int c = 0; c < 6; ++c) v[c] += __shfl_down(v[c], off, 64);

  __shared__ float wsum[4][6];
  __shared__ float bc[2];
  if (lane == 0)
#pragma unroll
    for (int c = 0; c < 6; ++c) wsum[wave][c] = v[c];
  __syncthreads();
  if (t == 0) {
    float r[6];
#pragma unroll
    for (int c = 0; c < 6; ++c) r[c] = wsum[0][c] + wsum[1][c] + wsum[2][c] + wsum[3][c];
    float h0 = fmaxf(r[0] + gb1[0], 0.f);
    float h1 = fmaxf(r[1] + gb1[1], 0.f);
    float h2 = fmaxf(r[2] + gb1[2], 0.f);
    float h3 = fmaxf(r[3] + gb1[3], 0.f);
    float lg[4];
#pragma unroll
    for (int e = 0; e < 4; ++e) {
      float val = h0*gw2[0*4+e] + h1*gw2[1*4+e] + h2*gw2[2*4+e] + h3*gw2[3*4+e] + gb2[e];
      lg[e] = (dmask[e] == 0) ? -1.0e9f : val;
    }
    float m = fmaxf(fmaxf(lg[0], lg[1]), fmaxf(lg[2], lg[3]));
    float e0 = expf(lg[0]-m), e1 = expf(lg[1]-m), e2 = expf(lg[2]-m), e3 = expf(lg[3]-m);
    float inv = 1.f / (e0 + e1 + e2 + e3);
    float4 wv; wv.x = e0*inv; wv.y = e1*inv; wv.z = e2*inv; wv.w = 0.f;
    *(float4*)(wout + (size_t)row * 4) = wv;
    float mean = r[4] * (1.f/1024.f);
    float var  = r[5] * (1.f/1024.f) - mean * mean;
    bc[0] = mean; bc[1] = rsqrtf(var + 1e-6f);
  }
  __syncthreads();
  const float mean = bc[0], rstd = bc[1];

  const float4 sbv = *(const float4*)(sb + t*4);
  const float4 bbv = *(const float4*)(bb + t*4);
  const float4 siv = *(const float4*)(si + t*4);
  const float4 biv = *(const float4*)(bi + t*4);
  const float sbs[4] = {sbv.x, sbv.y, sbv.z, sbv.w};
  const float bbs[4] = {bbv.x, bbv.y, bbv.z, bbv.w};
  const float sis[4] = {siv.x, siv.y, siv.z, siv.w};
  const float bis[4] = {biv.x, biv.y, biv.z, biv.w};
  ushort4 zb, zi;
  unsigned short zbv[4], ziv[4];
#pragma unroll
  for (int j = 0; j < 4; ++j) {
    float xn = (xs[j] - mean) * rstd;
    zbv[j] = f2bf(xn * sbs[j] + bbs[j]);
    ziv[j] = f2bf(xn * sis[j] + bis[j]);
  }
  zb.x = zbv[0]; zb.y = zbv[1]; zb.z = zbv[2]; zb.w = zbv[3];
  zi.x = ziv[0]; zi.y = ziv[1]; zi.z = ziv[2]; zi.w = ziv[3];
  *(ushort4*)(z + (size_t)(2 * row) * 1024 + t * 4) = zb;
  *(ushort4*)(z + (size_t)(2 * row + 1) * 1024 + t * 4) = zi;
}

// ---------- kernel 2: f32 (R,C) -> bf16 transposed (C,R) ----------
__global__ __launch_bounds__(256)
void k_transpose_bf16(const float* __restrict__ src, unsigned short* __restrict__ dst,
                      int R, int C)
{
  __shared__ float tile[32][33];
  const int tx = threadIdx.x & 31, ty = threadIdx.x >> 5;
  const int c0 = blockIdx.x * 32, r0 = blockIdx.y * 32;
#pragma unroll
  for (int j = 0; j < 32; j += 8)
    tile[ty + j][tx] = src[(size_t)(r0 + ty + j) * C + c0 + tx];
  __syncthreads();
#pragma unroll
  for (int j = 0; j < 32; j += 8)
    dst[(size_t)(c0 + ty + j) * R + r0 + tx] = f2bf(tile[tx][ty + j]);
}

// ---------- kernel 3: 256x256 bf16 GEMM, 1-barrier/phase, LDS-retiled epilogue ----------
// MODE 0: C = relu(A@Bt^T + bias) -> bf16, coalesced via LDS retile
// MODE 1: fused mix epilogue: out[orow] = x[orow]*(1+w0) + w1*(acc_book+bias) + w2*(acc_iwslt+bias)
//         (M interleaved: even rows book, odd rows iwslt; lane's j-pairs are variant pairs)
template <int MODE, int K, int NBX>
__global__ __launch_bounds__(512, 2)
void gemm256(const unsigned short* __restrict__ A,
             const unsigned short* __restrict__ Bt,
             const float* __restrict__ bias,
             unsigned short* __restrict__ Cb,
             const float* __restrict__ x,
             const float* __restrict__ wgt,
             float* __restrict__ outp)
{
  constexpr int NKT = K / 64;
  constexpr int N = NBX * 256;
  __shared__ __align__(16) char lds[131072];

  const int tid = threadIdx.x;
  const int wave = tid >> 6, lane = tid & 63;
  const int lr = lane & 15, lk = lane >> 4;
  const int wm = wave >> 2, wn = wave & 3;

  // XCD-aware bijective block swizzle (gridDim.x % 8 == 0)
  const int cpx = (int)gridDim.x >> 3;
  const int flat = (int)blockIdx.x;
  const int swz = (flat & 7) * cpx + (flat >> 3);
  const int bm0 = (swz / NBX) * 256;
  const int bn0 = (swz % NBX) * 256;

  const int srow = tid >> 3;
  const int schunk = ((tid & 7) ^ (srow & 7)) * 8;
  const unsigned short* aSrc = A + (size_t)(bm0 + srow) * K + schunk;
  const unsigned short* bSrc = Bt + (size_t)(bn0 + srow) * K + schunk;
  const int ldsWaveOff = wave * 1024;

  const int xorv = (lr & 7) << 4;
  const int koff0 = (lk * 16) ^ xorv;
  const int koff1 = (64 + lk * 16) ^ xorv;
  const int arowB = wm * 128 + lr;
  const int browB = wn * 64 + lr;

  f32x4 acc[8][4] = {};

  auto stage = [&](int j) {
    if (j >= 4 * NKT) return;
    const int tile = j >> 2, h = j & 3;
    const unsigned short* s = (h < 2 ? bSrc : aSrc) + (size_t)((h & 1) * 128) * K + tile * 64;
    char* d = lds + ((tile & 1) << 16) + ((h < 2) ? 32768 : 0) + ((h & 1) << 14) + ldsWaveOff;
    gload16(s, d);
    gload16(s + (size_t)64 * K, d + 8192);
  };

  stage(0); stage(1); stage(2); stage(3); stage(4); stage(5);
  asm volatile("s_waitcnt vmcnt(4)" ::: "memory");
  __builtin_amdgcn_s_barrier();

#pragma unroll 2
  for (int t = 0; t < NKT; ++t) {
    const char* curA = lds + ((t & 1) << 16);
    const char* curB = curA + 32768;
    const int jb = 6 + 4 * t;
    bf16x8 bf[4][2];
    bf16x8 af[2][2];

#pragma unroll
    for (int q = 0; q < 4; ++q) {
      if (q == 0) {
#pragma unroll
        for (int ni = 0; ni < 4; ++ni) {
          bf[ni][0] = *(const bf16x8*)(curB + (browB + ni * 16) * 128 + koff0);
          bf[ni][1] = *(const bf16x8*)(curB + (browB + ni * 16) * 128 + koff1);
        }
      }
#pragma unroll
      for (int i = 0; i < 2; ++i) {
        af[i][0] = *(const bf16x8*)(curA + (arowB + (2 * q + i) * 16) * 128 + koff0);
        af[i][1] = *(const bf16x8*)(curA + (arowB + (2 * q + i) * 16) * 128 + koff1);
      }
      stage(jb + q);
      if (q == 3) {
        if (t < NKT - 2)       asm volatile("s_waitcnt vmcnt(4)" ::: "memory");
        else if (t == NKT - 2) asm volatile("s_waitcnt vmcnt(0)" ::: "memory");
      }
      __builtin_amdgcn_s_barrier();
      asm volatile("s_waitcnt lgkmcnt(0)" ::: "memory");
      __builtin_amdgcn_s_setprio(1);
#pragma unroll
      for (int i = 0; i < 2; ++i)
#pragma unroll
        for (int ni = 0; ni < 4; ++ni) {
          acc[2 * q + i][ni] = __builtin_amdgcn_mfma_f32_16x16x32_bf16(af[i][0], bf[ni][0], acc[2 * q + i][ni], 0, 0, 0);
          acc[2 * q + i][ni] = __builtin_amdgcn_mfma_f32_16x16x32_bf16(af[i][1], bf[ni][1], acc[2 * q + i][ni], 0, 0, 0);
        }
      __builtin_amdgcn_s_setprio(0);
      // no trailing barrier: next phase's ds_reads/stage overlap other waves' MFMA
    }
  }

  __syncthreads();   // all LDS reads done; buffer reused for C-retile

  if (MODE == 0) {
    // bf16 tile [256 rows][512B], swizzle byte ^= (row&7)<<4 (<=2-way on write, free)
#pragma unroll
    for (int ni = 0; ni < 4; ++ni) {
      const int colb = (wn * 64 + ni * 16 + lr) * 2;
      const float bv = bias[bn0 + wn * 64 + ni * 16 + lr];
#pragma unroll
      for (int mi = 0; mi < 8; ++mi) {
#pragma unroll
        for (int j = 0; j < 4; ++j) {
          const int row = wm * 128 + mi * 16 + lk * 4 + j;
          float v = fmaxf(acc[mi][ni][j] + bv, 0.f);
          *(unsigned short*)(lds + row * 512 + (colb ^ ((row & 7) << 4))) = f2bf(v);
        }
      }
    }
    __syncthreads();
#pragma unroll
    for (int s = 0; s < 16; ++s) {
      const int row = wave * 32 + s * 2 + (lane >> 5);
      const int c = lane & 31;
      bf16x8 vv = *(const bf16x8*)(lds + row * 512 + ((c * 16) ^ ((row & 7) << 4)));
      *(bf16x8*)(Cb + (size_t)(bm0 + row) * N + bn0 + c * 8) = vv;
    }
  } else {
    // mix epilogue: f32 tile [128 orows][1024B], swizzle byte ^= (lrow&6)<<5 (<=2-way)
    const int orbase = bm0 >> 1;
#pragma unroll
    for (int mi = 0; mi < 8; ++mi) {
      const int lr0 = wm * 64 + mi * 8 + lk * 2;
      const float4 wa = *(const float4*)(wgt + (size_t)(orbase + lr0) * 4);
      const float4 wb = *(const float4*)(wgt + (size_t)(orbase + lr0 + 1) * 4);
#pragma unroll
      for (int ni = 0; ni < 4; ++ni) {
        const int colb = (wn * 64 + ni * 16 + lr) * 4;
        const float bv = bias[bn0 + wn * 64 + ni * 16 + lr];
        float m0 = wa.y * (acc[mi][ni][0] + bv) + wa.z * (acc[mi][ni][1] + bv);
        float m1 = wb.y * (acc[mi][ni][2] + bv) + wb.z * (acc[mi][ni][3] + bv);
        *(float*)(lds + (size_t)lr0 * 1024 + (colb ^ ((lr0 & 6) << 5))) = m0;
        *(float*)(lds + (size_t)(lr0 + 1) * 1024 + (colb ^ (((lr0 + 1) & 6) << 5))) = m1;
      }
    }
    __syncthreads();
#pragma unroll
    for (int s = 0; s < 16; ++s) {
      const int lrow = wave * 16 + s;
      const int gor = orbase + lrow;
      f32x4 m = *(const f32x4*)(lds + (size_t)lrow * 1024 + ((lane * 16) ^ ((lrow & 6) << 5)));
      const float4 xv = *(const float4*)(x + (size_t)gor * 1024 + bn0 + lane * 4);
      const float w0 = wgt[(size_t)gor * 4];
      f32x4 o;
      o[0] = xv.x * (1.f + w0) + m[0];
      o[1] = xv.y * (1.f + w0) + m[1];
      o[2] = xv.z * (1.f + w0) + m[2];
      o[3] = xv.w * (1.f + w0) + m[3];
      *(f32x4*)(outp + (size_t)gor * 1024 + bn0 + lane * 4) = o;
    }
  }
}

// ---------- launch ----------
extern "C" void kernel_launch(void* const* d_in, const int* in_sizes, int n_in,
                              void* d_out, int out_size, void* d_ws, size_t ws_size,
                              hipStream_t stream) {
  const float* x    = (const float*)d_in[0];
  const int*   dm   = (const int*)  d_in[1];
  const float* gw1  = (const float*)d_in[2];
  const float* gb1  = (const float*)d_in[3];
  const float* gw2  = (const float*)d_in[4];
  const float* gb2  = (const float*)d_in[5];
  const float* lsb  = (const float*)d_in[6];
  const float* lbb  = (const float*)d_in[7];
  const float* lsi  = (const float*)d_in[8];
  const float* lbi  = (const float*)d_in[9];
  const float* aw1  = (const float*)d_in[10];
  const float* ab1  = (const float*)d_in[11];
  const float* aw2  = (const float*)d_in[12];
  const float* ab2  = (const float*)d_in[13];
  float* out = (float*)d_out;

  char* ws = (char*)d_ws;
  float*          wgt  = (float*)(ws + 0);                                     // 128KB
  unsigned short* z    = (unsigned short*)(ws + 131072);                       // 32MB (interleaved)
  unsigned short* w1t  = (unsigned short*)(ws + 131072 + 33554432);            // 4MB
  unsigned short* w2t  = (unsigned short*)(ws + 131072 + 33554432 + 4194304);  // 4MB
  unsigned short* hbuf = (unsigned short*)(ws + 131072 + 33554432 + 8388608);  // 64MB

  k_gate_ln<<<8192, 256, 0, stream>>>(x, dm, gw1, gb1, gw2, gb2,
                                      lsb, lbb, lsi, lbi, wgt, z);
  k_transpose_bf16<<<dim3(2048/32, 1024/32), 256, 0, stream>>>(aw1, w1t, 1024, 2048);
  k_transpose_bf16<<<dim3(1024/32, 2048/32), 256, 0, stream>>>(aw2, w2t, 2048, 1024);
  // GEMM1: h = relu(z @ w1 + b1)   [16384 x 2048], K=1024
  gemm256<0, 1024, 8><<<512, 512, 0, stream>>>(z, w1t, ab1, hbuf, nullptr, nullptr, nullptr);
  // GEMM2 (+fused mix): out = x*(1+w0) + w1*ab + w2*ai   [rows 8192 x 1024], K=2048
  gemm256<1, 2048, 4><<<256, 512, 0, stream>>>(hbuf, w2t, ab2, nullptr, x, wgt, out);
}

// Round 5
// 258.828 us; speedup vs baseline: 1.3535x; 1.0097x over previous
//
#include <hip/hip_runtime.h>
#include <stdint.h>

// ---------- helpers ----------
typedef __attribute__((ext_vector_type(8))) short bf16x8;
typedef __attribute__((ext_vector_type(4))) float f32x4;

__device__ __forceinline__ unsigned short f2bf(float f) {
  union { float f; unsigned u; } v; v.f = f;
  unsigned r = v.u + 0x7fffu + ((v.u >> 16) & 1u);   // RNE
  return (unsigned short)(r >> 16);
}
__device__ __forceinline__ float bf2f(unsigned short u) {
  union { unsigned u; float f; } v; v.u = ((unsigned)u) << 16; return v.f;
}
__device__ __forceinline__ void gload16(const void* g, void* l) {
  __builtin_amdgcn_global_load_lds(
      (const __attribute__((address_space(1))) unsigned int*)(uintptr_t)g,
      (__attribute__((address_space(3))) unsigned int*)(uintptr_t)l,
      16, 0, 0);
}

// ---------- kernel 1: gate + LN, one wave per row, no barriers ----------
// z rows interleaved: 2*row = book, 2*row+1 = iwslt
__global__ __launch_bounds__(256)
void k_gate_ln(const float* __restrict__ x, const int* __restrict__ dmask,
               const float* __restrict__ gw1, const float* __restrict__ gb1,
               const float* __restrict__ gw2, const float* __restrict__ gb2,
               const float* __restrict__ sb, const float* __restrict__ bb,
               const float* __restrict__ si, const float* __restrict__ bi,
               float* __restrict__ wout,          // [rows][4] f32: w0,w1,w2,0
               unsigned short* __restrict__ z)    // [2*rows][1024] bf16 interleaved
{
  const int lane = threadIdx.x & 63;
  const int row = blockIdx.x * 4 + (threadIdx.x >> 6);
  const float* xr = x + (size_t)row * 1024;

  float4 xv[4];
  float p0 = 0.f, p1 = 0.f, p2 = 0.f, p3 = 0.f, s = 0.f, ss = 0.f;
#pragma unroll
  for (int j = 0; j < 4; ++j) {
    const int i0 = lane * 4 + j * 256;
    xv[j] = *(const float4*)(xr + i0);
    const float xc[4] = {xv[j].x, xv[j].y, xv[j].z, xv[j].w};
#pragma unroll
    for (int c = 0; c < 4; ++c) {
      const float4 w = *(const float4*)(gw1 + (size_t)(i0 + c) * 4);
      p0 += xc[c] * w.x; p1 += xc[c] * w.y; p2 += xc[c] * w.z; p3 += xc[c] * w.w;
      s += xc[c]; ss += xc[c] * xc[c];
    }
  }
  // butterfly reduce: all 64 lanes end with the full-row sums
#pragma unroll
  for (int m = 32; m >= 1; m >>= 1) {
    p0 += __shfl_xor(p0, m, 64); p1 += __shfl_xor(p1, m, 64);
    p2 += __shfl_xor(p2, m, 64); p3 += __shfl_xor(p3, m, 64);
    s  += __shfl_xor(s,  m, 64); ss += __shfl_xor(ss, m, 64);
  }
  // gate head, computed redundantly by all lanes (uniform)
  const float h0 = fmaxf(p0 + gb1[0], 0.f), h1 = fmaxf(p1 + gb1[1], 0.f);
  const float h2 = fmaxf(p2 + gb1[2], 0.f), h3 = fmaxf(p3 + gb1[3], 0.f);
  float lg[4];
#pragma unroll
  for (int e = 0; e < 4; ++e) {
    float val = h0 * gw2[e] + h1 * gw2[4 + e] + h2 * gw2[8 + e] + h3 * gw2[12 + e] + gb2[e];
    lg[e] = (dmask[e] == 0) ? -1.0e9f : val;
  }
  const float mx = fmaxf(fmaxf(lg[0], lg[1]), fmaxf(lg[2], lg[3]));
  const float e0 = expf(lg[0] - mx), e1 = expf(lg[1] - mx);
  const float e2 = expf(lg[2] - mx), e3 = expf(lg[3] - mx);
  const float inv = 1.f / (e0 + e1 + e2 + e3);
  if (lane == 0) {
    float4 wv; wv.x = e0 * inv; wv.y = e1 * inv; wv.z = e2 * inv; wv.w = 0.f;
    *(float4*)(wout + (size_t)row * 4) = wv;
  }
  const float mean = s * (1.f / 1024.f);
  const float rstd = rsqrtf(ss * (1.f / 1024.f) - mean * mean + 1e-6f);

#pragma unroll
  for (int j = 0; j < 4; ++j) {
    const int i0 = lane * 4 + j * 256;
    const float4 sbv = *(const float4*)(sb + i0);
    const float4 bbv = *(const float4*)(bb + i0);
    const float4 siv = *(const float4*)(si + i0);
    const float4 biv = *(const float4*)(bi + i0);
    const float xc[4] = {xv[j].x, xv[j].y, xv[j].z, xv[j].w};
    const float sbs[4] = {sbv.x, sbv.y, sbv.z, sbv.w};
    const float bbs[4] = {bbv.x, bbv.y, bbv.z, bbv.w};
    const float sis[4] = {siv.x, siv.y, siv.z, siv.w};
    const float bis[4] = {biv.x, biv.y, biv.z, biv.w};
    ushort4 zb, zi;
    unsigned short zbv[4], ziv[4];
#pragma unroll
    for (int c = 0; c < 4; ++c) {
      const float xn = (xc[c] - mean) * rstd;
      zbv[c] = f2bf(xn * sbs[c] + bbs[c]);
      ziv[c] = f2bf(xn * sis[c] + bis[c]);
    }
    zb.x = zbv[0]; zb.y = zbv[1]; zb.z = zbv[2]; zb.w = zbv[3];
    zi.x = ziv[0]; zi.y = ziv[1]; zi.z = ziv[2]; zi.w = ziv[3];
    *(ushort4*)(z + (size_t)(2 * row) * 1024 + i0) = zb;
    *(ushort4*)(z + (size_t)(2 * row + 1) * 1024 + i0) = zi;
  }
}

// ---------- kernel 2: f32 (R,C) -> bf16 transposed (C,R) ----------
__global__ __launch_bounds__(256)
void k_transpose_bf16(const float* __restrict__ src, unsigned short* __restrict__ dst,
                      int R, int C)
{
  __shared__ float tile[32][33];
  const int tx = threadIdx.x & 31, ty = threadIdx.x >> 5;
  const int c0 = blockIdx.x * 32, r0 = blockIdx.y * 32;
#pragma unroll
  for (int j = 0; j < 32; j += 8)
    tile[ty + j][tx] = src[(size_t)(r0 + ty + j) * C + c0 + tx];
  __syncthreads();
#pragma unroll
  for (int j = 0; j < 32; j += 8)
    dst[(size_t)(c0 + ty + j) * R + r0 + tx] = f2bf(tile[tx][ty + j]);
}

// ---------- kernel 3: 256x256 bf16 GEMM, ONE barrier per K-tile ----------
// MODE 0: C = relu(A@Bt^T + bias) -> bf16 (LDS-retiled coalesced store)
// MODE 1: fused mix epilogue (M interleaved book/iwslt pairs)
#define LOADA(dst, q) do {                                                            \
  dst[0][0] = *(const bf16x8*)(curA + (arowB + (2*(q)+0)*16) * 128 + koff0);          \
  dst[0][1] = *(const bf16x8*)(curA + (arowB + (2*(q)+0)*16) * 128 + koff1);          \
  dst[1][0] = *(const bf16x8*)(curA + (arowB + (2*(q)+1)*16) * 128 + koff0);          \
  dst[1][1] = *(const bf16x8*)(curA + (arowB + (2*(q)+1)*16) * 128 + koff1);          \
} while (0)

#define MFMAQ(src, q) do {                                                            \
  __builtin_amdgcn_s_setprio(1);                                                      \
  _Pragma("unroll")                                                                   \
  for (int i = 0; i < 2; ++i) {                                                       \
    _Pragma("unroll")                                                                 \
    for (int ni = 0; ni < 4; ++ni) {                                                  \
      acc[2*(q)+i][ni] = __builtin_amdgcn_mfma_f32_16x16x32_bf16(src[i][0], bf[ni][0], acc[2*(q)+i][ni], 0, 0, 0); \
      acc[2*(q)+i][ni] = __builtin_amdgcn_mfma_f32_16x16x32_bf16(src[i][1], bf[ni][1], acc[2*(q)+i][ni], 0, 0, 0); \
    } }                                                                               \
  __builtin_amdgcn_s_setprio(0);                                                      \
} while (0)

template <int MODE, int K, int NBX>
__global__ __launch_bounds__(512, 2)
void gemm256(const unsigned short* __restrict__ A,
             const unsigned short* __restrict__ Bt,
             const float* __restrict__ bias,
             unsigned short* __restrict__ Cb,
             const float* __restrict__ x,
             const float* __restrict__ wgt,
             float* __restrict__ outp)
{
  constexpr int NKT = K / 64;
  constexpr int N = NBX * 256;
  __shared__ __align__(16) char lds[131072];

  const int tid = threadIdx.x;
  const int wave = tid >> 6, lane = tid & 63;
  const int lr = lane & 15, lk = lane >> 4;
  const int wm = wave >> 2, wn = wave & 3;

  // XCD-aware bijective block swizzle (gridDim.x % 8 == 0)
  const int cpx = (int)gridDim.x >> 3;
  const int flat = (int)blockIdx.x;
  const int swz = (flat & 7) * cpx + (flat >> 3);
  const int bm0 = (swz / NBX) * 256;
  const int bn0 = (swz % NBX) * 256;

  // staging: inverse-swizzled global source, linear LDS dest (rule #21)
  const int srow = tid >> 3;
  const int schunk = ((tid & 7) ^ (srow & 7)) * 8;
  const unsigned short* aSrc = A + (size_t)(bm0 + srow) * K + schunk;
  const unsigned short* bSrc = Bt + (size_t)(bn0 + srow) * K + schunk;
  const int ldsWaveOff = wave * 1024;

  // read-side swizzled k-offsets
  const int xorv = (lr & 7) << 4;
  const int koff0 = (lk * 16) ^ xorv;
  const int koff1 = (64 + lk * 16) ^ xorv;
  const int arowB = wm * 128 + lr;
  const int browB = wn * 64 + lr;

  f32x4 acc[8][4] = {};

  auto stage_tile = [&](int tt) {
#pragma unroll
    for (int h = 0; h < 4; ++h) {   // {B-lo, B-hi, A-lo, A-hi}
      const unsigned short* sp = (h < 2 ? bSrc : aSrc) + (size_t)((h & 1) * 128) * K + tt * 64;
      char* d = lds + ((tt & 1) << 16) + ((h < 2) ? 32768 : 0) + ((h & 1) << 14) + ldsWaveOff;
      gload16(sp, d);
      gload16(sp + (size_t)64 * K, d + 8192);
    }
  };

  stage_tile(0);
  asm volatile("s_waitcnt vmcnt(0)" ::: "memory");
  __builtin_amdgcn_s_barrier();

#pragma unroll 2
  for (int t = 0; t < NKT; ++t) {
    const char* curA = lds + ((t & 1) << 16);
    const char* curB = curA + 32768;
    if (t + 1 < NKT) stage_tile(t + 1);   // whole next tile, issued a full tile early

    bf16x8 bf[4][2];
#pragma unroll
    for (int ni = 0; ni < 4; ++ni) {
      bf[ni][0] = *(const bf16x8*)(curB + (browB + ni * 16) * 128 + koff0);
      bf[ni][1] = *(const bf16x8*)(curB + (browB + ni * 16) * 128 + koff1);
    }
    bf16x8 a0[2][2], a1[2][2];
    LOADA(a0, 0);
    LOADA(a1, 1);
    MFMAQ(a0, 0);  LOADA(a0, 2);
    MFMAQ(a1, 1);  LOADA(a1, 3);
    MFMAQ(a0, 2);
    MFMAQ(a1, 3);

    asm volatile("s_waitcnt vmcnt(0)" ::: "memory");   // next tile landed (issued ~1 tile ago)
    __builtin_amdgcn_s_barrier();
  }

  __syncthreads();   // LDS reuse for epilogue retile

  if (MODE == 0) {
    // bf16 tile [256 rows][512B], swizzle byte ^= (row&7)<<4 (<=2-way, free)
#pragma unroll
    for (int ni = 0; ni < 4; ++ni) {
      const int colb = (wn * 64 + ni * 16 + lr) * 2;
      const float bv = bias[bn0 + wn * 64 + ni * 16 + lr];
#pragma unroll
      for (int mi = 0; mi < 8; ++mi) {
#pragma unroll
        for (int j = 0; j < 4; ++j) {
          const int row = wm * 128 + mi * 16 + lk * 4 + j;
          float v = fmaxf(acc[mi][ni][j] + bv, 0.f);
          *(unsigned short*)(lds + row * 512 + (colb ^ ((row & 7) << 4))) = f2bf(v);
        }
      }
    }
    __syncthreads();
#pragma unroll
    for (int sx = 0; sx < 16; ++sx) {
      const int row = wave * 32 + sx * 2 + (lane >> 5);
      const int c = lane & 31;
      bf16x8 vv = *(const bf16x8*)(lds + row * 512 + ((c * 16) ^ ((row & 7) << 4)));
      *(bf16x8*)(Cb + (size_t)(bm0 + row) * N + bn0 + c * 8) = vv;
    }
  } else {
    // mix epilogue: f32 tile [128 orows][1024B], swizzle byte ^= (lrow&6)<<5 (<=2-way)
    const int orbase = bm0 >> 1;
#pragma unroll
    for (int mi = 0; mi < 8; ++mi) {
      const int lr0 = wm * 64 + mi * 8 + lk * 2;
      const float4 wa = *(const float4*)(wgt + (size_t)(orbase + lr0) * 4);
      const float4 wb = *(const float4*)(wgt + (size_t)(orbase + lr0 + 1) * 4);
#pragma unroll
      for (int ni = 0; ni < 4; ++ni) {
        const int colb = (wn * 64 + ni * 16 + lr) * 4;
        const float bv = bias[bn0 + wn * 64 + ni * 16 + lr];
        float m0 = wa.y * (acc[mi][ni][0] + bv) + wa.z * (acc[mi][ni][1] + bv);
        float m1 = wb.y * (acc[mi][ni][2] + bv) + wb.z * (acc[mi][ni][3] + bv);
        *(float*)(lds + (size_t)lr0 * 1024 + (colb ^ ((lr0 & 6) << 5))) = m0;
        *(float*)(lds + (size_t)(lr0 + 1) * 1024 + (colb ^ (((lr0 + 1) & 6) << 5))) = m1;
      }
    }
    __syncthreads();
#pragma unroll
    for (int sx = 0; sx < 16; ++sx) {
      const int lrow = wave * 16 + sx;
      const int gor = orbase + lrow;
      f32x4 m = *(const f32x4*)(lds + (size_t)lrow * 1024 + ((lane * 16) ^ ((lrow & 6) << 5)));
      const float4 xv = *(const float4*)(x + (size_t)gor * 1024 + bn0 + lane * 4);
      const float w0 = wgt[(size_t)gor * 4];
      f32x4 o;
      o[0] = xv.x * (1.f + w0) + m[0];
      o[1] = xv.y * (1.f + w0) + m[1];
      o[2] = xv.z * (1.f + w0) + m[2];
      o[3] = xv.w * (1.f + w0) + m[3];
      *(f32x4*)(outp + (size_t)gor * 1024 + bn0 + lane * 4) = o;
    }
  }
}

// ---------- launch ----------
extern "C" void kernel_launch(void* const* d_in, const int* in_sizes, int n_in,
                              void* d_out, int out_size, void* d_ws, size_t ws_size,
                              hipStream_t stream) {
  const float* x    = (const float*)d_in[0];
  const int*   dm   = (const int*)  d_in[1];
  const float* gw1  = (const float*)d_in[2];
  const float* gb1  = (const float*)d_in[3];
  const float* gw2  = (const float*)d_in[4];
  const float* gb2  = (const float*)d_in[5];
  const float* lsb  = (const float*)d_in[6];
  const float* lbb  = (const float*)d_in[7];
  const float* lsi  = (const float*)d_in[8];
  const float* lbi  = (const float*)d_in[9];
  const float* aw1  = (const float*)d_in[10];
  const float* ab1  = (const float*)d_in[11];
  const float* aw2  = (const float*)d_in[12];
  const float* ab2  = (const float*)d_in[13];
  float* out = (float*)d_out;

  char* ws = (char*)d_ws;
  float*          wgt  = (float*)(ws + 0);                                     // 128KB
  unsigned short* z    = (unsigned short*)(ws + 131072);                       // 32MB (interleaved)
  unsigned short* w1t  = (unsigned short*)(ws + 131072 + 33554432);            // 4MB
  unsigned short* w2t  = (unsigned short*)(ws + 131072 + 33554432 + 4194304);  // 4MB
  unsigned short* hbuf = (unsigned short*)(ws + 131072 + 33554432 + 8388608);  // 64MB

  k_gate_ln<<<2048, 256, 0, stream>>>(x, dm, gw1, gb1, gw2, gb2,
                                      lsb, lbb, lsi, lbi, wgt, z);
  k_transpose_bf16<<<dim3(2048/32, 1024/32), 256, 0, stream>>>(aw1, w1t, 1024, 2048);
  k_transpose_bf16<<<dim3(1024/32, 2048/32), 256, 0, stream>>>(aw2, w2t, 2048, 1024);
  // GEMM1: h = relu(z @ w1 + b1)   [16384 x 2048], K=1024
  gemm256<0, 1024, 8><<<512, 512, 0, stream>>>(z, w1t, ab1, hbuf, nullptr, nullptr, nullptr);
  // GEMM2 (+fused mix): out = x*(1+w0) + w1*ab + w2*ai   [rows 8192 x 1024], K=2048
  gemm256<1, 2048, 4><<<256, 512, 0, stream>>>(hbuf, w2t, ab2, nullptr, x, wgt, out);
}